// Round 25
// baseline (93.626 us; speedup 1.0000x reference)
//
#include <hip/hip_runtime.h>

#define NN 50000
#define NE 800000
#define KIN 512
#define HC 128
#define MAXDEG 64
#define NBK 782                      // dst buckets of 64 nodes
#define BCAP 1536                    // bucket region capacity (max sum ~1140)
#define EPC 2048                     // edges per chain block
#define NCB 391                      // chain blocks (391*2048 >= NE)

typedef float f32x4 __attribute__((ext_vector_type(4)));
typedef float f32x2 __attribute__((ext_vector_type(2)));
typedef short s16x8 __attribute__((ext_vector_type(8)));

__device__ __forceinline__ ushort f2bf(float f) {
  unsigned u = __float_as_uint(f);
  unsigned r = (u + 0x7FFFu + ((u >> 16) & 1u)) >> 16;  // RNE
  return (ushort)r;
}

__device__ __forceinline__ void gload_lds16(const void* g, void* l) {
  __builtin_amdgcn_global_load_lds((const __attribute__((address_space(1))) void*)g,
                                   (__attribute__((address_space(3))) void*)l, 16, 0, 0);
}

// JAX threefry2x32-20, partitionable path: ctr=(0,i), key=(0,42), bits=o0^o1
__device__ __forceinline__ unsigned tf_bits(unsigned i) {
  unsigned x0 = 0u, x1 = i;
  const unsigned ks0 = 0u, ks1 = 42u, ks2 = 0x1BD11BDAu ^ 42u;
#define R(r) { x0 += x1; x1 = (x1 << r) | (x1 >> (32 - r)); x1 ^= x0; }
  x0 += ks0; x1 += ks1;
  R(13) R(15) R(26) R(6)
  x0 += ks1; x1 += ks2 + 1u;
  R(17) R(29) R(16) R(24)
  x0 += ks2; x1 += ks0 + 2u;
  R(13) R(15) R(26) R(6)
  x0 += ks0; x1 += ks1 + 3u;
  R(17) R(29) R(16) R(24)
  x0 += ks1; x1 += ks2 + 4u;
  R(13) R(15) R(26) R(6)
  x0 += ks2; x1 += ks0 + 5u;
#undef R
  return x0 ^ x1;
}

// Wt transpose/convert + zero cursors + sentinel slots[NN]=0
__global__ void k_prep(const float* __restrict__ W, ushort* __restrict__ Wt,
                       int* __restrict__ slots, int* __restrict__ bcur) {
  int t = blockIdx.x * 256 + threadIdx.x;   // 65536 threads
  if (t < NBK) bcur[t] = 0;
  if (t == NBK) slots[NN] = 0;              // sentinel (rest set by k_csr)
  if (t < KIN * HC) {
    int c = t & (HC - 1), k = t >> 7;       // W row-major [k][c]
    Wt[c * KIN + k] = f2bf(W[t]);
  }
}

// Standalone chain (R24-verified body, full-machine): two-pass LDS-batched
// bucket scatter, 8-deep reg ILP, one cursor claim per touched bucket/block.
__global__ void k_chain(const int* __restrict__ ei, int* __restrict__ bcur,
                        unsigned* __restrict__ region) {
  __shared__ int lcnt[NBK];
  __shared__ int gb[NBK];
  __shared__ int lcnt2[NBK];
  const int tid = threadIdx.x;
  for (int i = tid; i < NBK; i += 256) { lcnt[i] = 0; lcnt2[i] = 0; }
  __syncthreads();
  const int e0 = blockIdx.x * EPC + tid;
  int dc[8];                                // 8 independent loads (ILP)
#pragma unroll
  for (int k = 0; k < 8; k++) {
    int e = e0 + k * 256;
    dc[k] = (e < NE) ? ei[NE + e] : -1;
  }
#pragma unroll
  for (int k = 0; k < 8; k++)
    if (dc[k] >= 0) atomicAdd(&lcnt[dc[k] >> 6], 1);
  __syncthreads();
  for (int i = tid; i < NBK; i += 256)
    if (lcnt[i]) gb[i] = atomicAdd(&bcur[i], lcnt[i]);  // batched claim
  __syncthreads();
  int sc[8];                                // src reload (L2-hot)
#pragma unroll
  for (int k = 0; k < 8; k++) {
    int e = e0 + k * 256;
    sc[k] = (e < NE) ? ei[e] : -1;
  }
#pragma unroll
  for (int k = 0; k < 8; k++) {
    if (dc[k] >= 0) {
      int bkt = dc[k] >> 6;
      int r = atomicAdd(&lcnt2[bkt], 1);
      int p = gb[bkt] + r;
      if (p < BCAP)
        region[(size_t)bkt * BCAP + p] = ((unsigned)dc[k] << 16) | (unsigned)sc[k];
    }
  }
}

// Standalone GEMM (R22-verified body): xb = feats @ W unscaled bf16 (rows>=NN
// zero sentinel) + dropout-mask bytes for this tile's rows.
__launch_bounds__(256, 6)
__global__ void k_gemm(const float* __restrict__ feats, const ushort* __restrict__ Wt,
                       ushort* __restrict__ xb, unsigned char* __restrict__ mask) {
  __shared__ __align__(16) float  As[32 * 64];    // 8 KB, 256 B/row (16 chunks)
  __shared__ __align__(16) ushort Bs[128 * 64];   // 16 KB, 128 B/row (8 chunks)
  const int g = blockIdx.x;                       // 1563 tiles
  const int tid = threadIdx.x;
  const int lane = tid & 63;
  const int w = tid >> 6;
  const int wm = w >> 1, wn = w & 1;
  const int rbase = g * 32;                       // rows 0..50015

  {
    int mb = rbase * 16 + tid;
#pragma unroll
    for (int h = 0; h < 2; ++h, mb += 256) {
      if (mb < NN * 16) {
        unsigned by = 0;
#pragma unroll
        for (int k = 0; k < 8; k++)
          by |= (tf_bits(8u * (unsigned)mb + k) >> 31) << k;   // bit=1 -> drop
        mask[mb] = (unsigned char)by;
      }
    }
  }

  f32x4 acc[4];
#pragma unroll
  for (int nt = 0; nt < 4; nt++) acc[nt] = f32x4{0.f, 0.f, 0.f, 0.f};

  const int a_rt = w * 8 + (lane >> 4);
  int a_gr[2];
#pragma unroll
  for (int i = 0; i < 2; i++) {
    int gr = rbase + a_rt + i * 4;
    a_gr[i] = (gr < NN) ? gr : NN - 1;
  }
  const int b_ct = w * 32 + (lane >> 3);              // + i*8 ; B tile col (Wt row)
  const int b_ch = ((lane & 7) ^ (b_ct & 7)) << 3;    // bf16 offset of swizzled chunk

  for (int ks = 0; ks < KIN; ks += 64) {
    __syncthreads();                               // prev-step LDS reads done
#pragma unroll
    for (int i = 0; i < 2; i++) {
      // A dest row ar = a_rt + i*4 -> (ar&7) = (a_rt&7) ^ ((i&1)<<2)
      int a_ch = ((lane & 15) ^ (a_rt & 7) ^ ((i & 1) << 2)) << 2;   // f32 offset
      gload_lds16(feats + (size_t)a_gr[i] * KIN + ks + a_ch,
                  (char*)As + (w * 8 + i * 4) * 256);
    }
#pragma unroll
    for (int i = 0; i < 4; i++)
      gload_lds16(Wt + (size_t)(b_ct + i * 8) * KIN + ks + b_ch,
                  (char*)Bs + (w * 32 + i * 8) * 128);
    __syncthreads();                               // staged (vmcnt drained by barrier)
#pragma unroll
    for (int kk = 0; kk < 2; kk++) {
      s16x8 bfr[4];
#pragma unroll
      for (int nt = 0; nt < 4; nt++) {
        int c = wn * 64 + nt * 16 + (lane & 15);
        int ch = (kk * 4 + (lane >> 4)) ^ (c & 7);
        bfr[nt] = *(const s16x8*)((const char*)Bs + c * 128 + ch * 16);
      }
      int r = wm * 16 + (lane & 15);
      int c0 = kk * 8 + (lane >> 4) * 2;
      f32x4 f0 = *(const f32x4*)((const char*)As + r * 256 + ((c0 ^ (r & 7)) * 16));
      f32x4 f1 = *(const f32x4*)((const char*)As + r * 256 + (((c0 + 1) ^ (r & 7)) * 16));
      s16x8 af;
#pragma unroll
      for (int t = 0; t < 4; t++) {
        af[t]     = (short)f2bf(f0[t]);
        af[t + 4] = (short)f2bf(f1[t]);
      }
#pragma unroll
      for (int nt = 0; nt < 4; nt++)
        acc[nt] = __builtin_amdgcn_mfma_f32_16x16x32_bf16(af, bfr[nt], acc[nt], 0, 0, 0);
    }
  }
  {
    int rb = rbase + wm * 16 + (lane >> 4) * 4;
#pragma unroll
    for (int j = 0; j < 4; j++) {
      int r = rb + j;
      bool ok = (r < NN);
#pragma unroll
      for (int nt = 0; nt < 4; nt++) {
        int c = wn * 64 + nt * 16 + (lane & 15);
        xb[(size_t)r * HC + c] = ok ? f2bf(acc[nt][j]) : (ushort)0;
      }
    }
  }
}

// region -> per-node csr16 + degrees. One block per bucket: LDS slot counters,
// block-exclusive 8 KB csr16 window -> burst-dense stores. (R19-verified body)
__global__ void k_csr(const unsigned* __restrict__ region, const int* __restrict__ bcur,
                      ushort* __restrict__ csr16, int* __restrict__ slots) {
  __shared__ int lc[64];
  const int bkt = blockIdx.x;               // 0..781
  const int tid = threadIdx.x;
  if (tid < 64) lc[tid] = 0;
  __syncthreads();
  int cnt = bcur[bkt]; if (cnt > BCAP) cnt = BCAP;
  for (int i = tid; i < cnt; i += 256) {
    unsigned u = region[(size_t)bkt * BCAP + i];
    int d = u >> 16, s = u & 0xFFFFu;
    int slot = atomicAdd(&lc[d & 63], 1);
    if (slot < MAXDEG) csr16[(size_t)d * MAXDEG + slot] = (ushort)s;
  }
  __syncthreads();
  if (tid < 64) {
    int n = bkt * 64 + tid;
    if (n < NN) slots[n] = lc[tid];         // true degree
  }
}

// one wave per node, 4-way edge split, direct csr16 (R17-verified body):
// sum of x[src]*dinv[src], dinv f32 from L2-hot slots[]; dn+bias+relu+mask
// after reduce. Sentinel row NN (zeros), slots[NN]=0.
__global__ void k_agg(const ushort* __restrict__ xb, const int* __restrict__ slots,
                      const ushort* __restrict__ csr16,
                      const unsigned char* __restrict__ mask,
                      const float* __restrict__ b, float* __restrict__ out) {
  int n = blockIdx.x * 4 + (threadIdx.x >> 6);
  if (n >= NN) return;
  const int lane = threadIdx.x & 63;
  const int grp = lane >> 4;          // edge slot (0..3)
  const int q = lane & 15;            // channels q*8 .. q*8+7
  const int degt = slots[n];          // true degree
  const int deg = (degt < MAXDEG) ? degt : MAXDEG;
  const float dn = rsqrtf((float)(degt + 1));

  float a0, a1, a2, a3, a4, a5, a6, a7;
  {
    uint4 sv = *(const uint4*)(xb + (size_t)n * HC + q * 8);
    float z = (grp == 0) ? dn : 0.0f; // self term in group 0 (final *dn -> dn^2)
    a0 = __uint_as_float(sv.x << 16)         * z;
    a1 = __uint_as_float(sv.x & 0xFFFF0000u) * z;
    a2 = __uint_as_float(sv.y << 16)         * z;
    a3 = __uint_as_float(sv.y & 0xFFFF0000u) * z;
    a4 = __uint_as_float(sv.z << 16)         * z;
    a5 = __uint_as_float(sv.z & 0xFFFF0000u) * z;
    a6 = __uint_as_float(sv.w << 16)         * z;
    a7 = __uint_as_float(sv.w & 0xFFFF0000u) * z;
  }

  const ushort* cp = csr16 + (size_t)n * MAXDEG;
  const int np = (deg + 3) >> 2;      // quads
  unsigned s0 = (grp < deg) ? cp[grp] : (unsigned)NN;   // sentinel = zero row
  uint4 g = *(const uint4*)(xb + (size_t)s0 * HC + q * 8);
  int c0 = slots[s0];
  for (int j = 0; j < np; ++j) {
    int idx = 4 * j + 4 + grp;
    unsigned s1 = (idx < deg) ? cp[idx] : (unsigned)NN;
    uint4 gn = *(const uint4*)(xb + (size_t)s1 * HC + q * 8);
    int c1 = slots[s1];
    float di = rsqrtf((float)(c0 + 1));   // dinv[src], f32 precision
    a0 += __uint_as_float(g.x << 16)         * di;
    a1 += __uint_as_float(g.x & 0xFFFF0000u) * di;
    a2 += __uint_as_float(g.y << 16)         * di;
    a3 += __uint_as_float(g.y & 0xFFFF0000u) * di;
    a4 += __uint_as_float(g.z << 16)         * di;
    a5 += __uint_as_float(g.z & 0xFFFF0000u) * di;
    a6 += __uint_as_float(g.w << 16)         * di;
    a7 += __uint_as_float(g.w & 0xFFFF0000u) * di;
    g = gn; c0 = c1;
  }
#define RED(A) A += __shfl_xor(A, 16); A += __shfl_xor(A, 32);
  RED(a0) RED(a1) RED(a2) RED(a3) RED(a4) RED(a5) RED(a6) RED(a7)
#undef RED
  float sx = (grp == 0) ? a0 : (grp == 1) ? a2 : (grp == 2) ? a4 : a6;
  float sy = (grp == 0) ? a1 : (grp == 1) ? a3 : (grp == 2) ? a5 : a7;
  int i0 = n * HC + q * 8 + 2 * grp;
  f32x2 bb = *(const f32x2*)(b + q * 8 + 2 * grp);
  float vx = fmaxf(sx * dn + bb.x, 0.f) * 2.f;
  float vy = fmaxf(sy * dn + bb.y, 0.f) * 2.f;
  unsigned m = mask[n * 16 + q];      // drop bits for elements q*8 .. q*8+7
  f32x2 r;
  r.x = ((m >> (2 * grp))     & 1u) ? 0.f : vx;
  r.y = ((m >> (2 * grp + 1)) & 1u) ? 0.f : vy;
  *(f32x2*)(out + i0) = r;
}

extern "C" void kernel_launch(void* const* d_in, const int* in_sizes, int n_in,
                              void* d_out, int out_size, void* d_ws, size_t ws_size,
                              hipStream_t stream) {
  const float* feats = (const float*)d_in[0];
  const float* W     = (const float*)d_in[1];
  const float* b     = (const float*)d_in[2];
  const int*   ei    = (const int*)d_in[3];
  float* out = (float*)d_out;

  // ws: xb[50016*HC] bf16 | Wt[HC*KIN] bf16 | slots[NN+1] i32 | mask[NE+512] u8
  //   | bcur[NBK] i32 | csr16[NN*64] u16 | region[NBK*BCAP] u32   (~25 MB)
  char* ws = (char*)d_ws;
  size_t o = 0;
  ushort*        xb     = (ushort*)(ws + o);        o += ((size_t)50016 * HC * 2 + 255) & ~(size_t)255;
  ushort*        Wt     = (ushort*)(ws + o);        o += ((size_t)HC * KIN * 2 + 255) & ~(size_t)255;
  int*           slots  = (int*)(ws + o);           o += ((size_t)(NN + 1) * 4 + 255) & ~(size_t)255;
  unsigned char* mask   = (unsigned char*)(ws + o); o += ((size_t)NE + 512 + 255) & ~(size_t)255;
  int*           bcur   = (int*)(ws + o);           o += ((size_t)NBK * 4 + 255) & ~(size_t)255;
  ushort*        csr16  = (ushort*)(ws + o);        o += ((size_t)NN * MAXDEG * 2 + 255) & ~(size_t)255;
  unsigned*      region = (unsigned*)(ws + o);

  k_prep <<<256, 256, 0, stream>>>(W, Wt, slots, bcur);
  k_chain<<<NCB, 256, 0, stream>>>(ei, bcur, region);
  k_gemm <<<1563, 256, 0, stream>>>(feats, Wt, xb, mask);
  k_csr  <<<NBK, 256, 0, stream>>>(region, bcur, csr16, slots);
  k_agg  <<<(NN + 3) / 4, 256, 0, stream>>>(xb, slots, csr16, mask, b, out);
}

// Round 26
// 85.013 us; speedup vs baseline: 1.1013x; 1.1013x over previous
//
#include <hip/hip_runtime.h>

#define NN 50000
#define NE 800000
#define KIN 512
#define HC 128
#define MAXDEG 64
#define NBKC 98                      // coarse dst buckets of 512 nodes
#define BCAPC 9216                   // bucket capacity (mean 8163 + 8 sigma)
#define EPB 4096                     // edges per chain block
#define NCH 196                      // chain blocks (196*4096 >= NE)

typedef float f32x4 __attribute__((ext_vector_type(4)));
typedef float f32x2 __attribute__((ext_vector_type(2)));
typedef short s16x8 __attribute__((ext_vector_type(8)));

__device__ __forceinline__ ushort f2bf(float f) {
  unsigned u = __float_as_uint(f);
  unsigned r = (u + 0x7FFFu + ((u >> 16) & 1u)) >> 16;  // RNE
  return (ushort)r;
}

__device__ __forceinline__ void gload_lds16(const void* g, void* l) {
  __builtin_amdgcn_global_load_lds((const __attribute__((address_space(1))) void*)g,
                                   (__attribute__((address_space(3))) void*)l, 16, 0, 0);
}

// JAX threefry2x32-20, partitionable path: ctr=(0,i), key=(0,42), bits=o0^o1
__device__ __forceinline__ unsigned tf_bits(unsigned i) {
  unsigned x0 = 0u, x1 = i;
  const unsigned ks0 = 0u, ks1 = 42u, ks2 = 0x1BD11BDAu ^ 42u;
#define R(r) { x0 += x1; x1 = (x1 << r) | (x1 >> (32 - r)); x1 ^= x0; }
  x0 += ks0; x1 += ks1;
  R(13) R(15) R(26) R(6)
  x0 += ks1; x1 += ks2 + 1u;
  R(17) R(29) R(16) R(24)
  x0 += ks2; x1 += ks0 + 2u;
  R(13) R(15) R(26) R(6)
  x0 += ks0; x1 += ks1 + 3u;
  R(17) R(29) R(16) R(24)
  x0 += ks1; x1 += ks2 + 4u;
  R(13) R(15) R(26) R(6)
  x0 += ks2; x1 += ks0 + 5u;
#undef R
  return x0 ^ x1;
}

// role map (R20-verified): 8-aligned groups alternate chain/task for first
// 2*nchg groups (spreads roles across XCDs under bid%8 dispatch), then task.
__device__ __forceinline__ void role_map(int bid, int nchg, bool* chain,
                                         int* cid, int* gid) {
  int g8 = bid >> 3, sub = bid & 7;
  if (g8 < 2 * nchg) {
    *chain = ((g8 & 1) == 0);
    int h = g8 >> 1;
    *cid = h * 8 + sub;
    *gid = h * 8 + sub;
  } else {
    *chain = false; *cid = 0;
    *gid = nchg * 8 + (g8 - 2 * nchg) * 8 + sub;
  }
}

// Wt transpose/convert + zero cursors + sentinel slots[NN]=0
__global__ void k_prep(const float* __restrict__ W, ushort* __restrict__ Wt,
                       int* __restrict__ slots, int* __restrict__ bcur) {
  int t = blockIdx.x * 256 + threadIdx.x;   // 65536 threads
  if (t < NBKC) bcur[t] = 0;
  if (t == NBKC) slots[NN] = 0;             // sentinel (rest set by k_csr)
  if (t < KIN * HC) {
    int c = t & (HC - 1), k = t >> 7;       // W row-major [k][c]
    Wt[c * KIN + k] = f2bf(W[t]);
  }
}

// GEMM tile body (R22-verified): xb = feats @ W unscaled bf16 (rows>=NN zero
// sentinel) + dropout-mask bytes. smem: [0,8K)=As, [8K,24K)=Bs.
__device__ void gemm_tile(int g, const float* __restrict__ feats,
                          const ushort* __restrict__ Wt, ushort* __restrict__ xb,
                          unsigned char* __restrict__ mask, char* smem) {
  float*  As = (float*)smem;                      // 32x64 f32, 256 B/row
  ushort* Bs = (ushort*)(smem + 8192);            // 128x64 bf16, 128 B/row
  const int tid = threadIdx.x;
  const int lane = tid & 63;
  const int w = tid >> 6;
  const int wm = w >> 1, wn = w & 1;
  const int rbase = g * 32;                       // rows 0..50015

  {
    int mb = rbase * 16 + tid;
#pragma unroll
    for (int h = 0; h < 2; ++h, mb += 256) {
      if (mb < NN * 16) {
        unsigned by = 0;
#pragma unroll
        for (int k = 0; k < 8; k++)
          by |= (tf_bits(8u * (unsigned)mb + k) >> 31) << k;   // bit=1 -> drop
        mask[mb] = (unsigned char)by;
      }
    }
  }

  f32x4 acc[4];
#pragma unroll
  for (int nt = 0; nt < 4; nt++) acc[nt] = f32x4{0.f, 0.f, 0.f, 0.f};

  const int a_rt = w * 8 + (lane >> 4);
  int a_gr[2];
#pragma unroll
  for (int i = 0; i < 2; i++) {
    int gr = rbase + a_rt + i * 4;
    a_gr[i] = (gr < NN) ? gr : NN - 1;
  }
  const int b_ct = w * 32 + (lane >> 3);              // + i*8 ; B tile col (Wt row)
  const int b_ch = ((lane & 7) ^ (b_ct & 7)) << 3;    // bf16 offset of swizzled chunk

  for (int ks = 0; ks < KIN; ks += 64) {
    __syncthreads();                               // prev-step LDS reads done
#pragma unroll
    for (int i = 0; i < 2; i++) {
      // A dest row ar = a_rt + i*4 -> (ar&7) = (a_rt&7) ^ ((i&1)<<2)
      int a_ch = ((lane & 15) ^ (a_rt & 7) ^ ((i & 1) << 2)) << 2;   // f32 offset
      gload_lds16(feats + (size_t)a_gr[i] * KIN + ks + a_ch,
                  (char*)As + (w * 8 + i * 4) * 256);
    }
#pragma unroll
    for (int i = 0; i < 4; i++)
      gload_lds16(Wt + (size_t)(b_ct + i * 8) * KIN + ks + b_ch,
                  (char*)Bs + (w * 32 + i * 8) * 128);
    __syncthreads();                               // staged (vmcnt drained by barrier)
#pragma unroll
    for (int kk = 0; kk < 2; kk++) {
      s16x8 bfr[4];
#pragma unroll
      for (int nt = 0; nt < 4; nt++) {
        int c = wn * 64 + nt * 16 + (lane & 15);
        int ch = (kk * 4 + (lane >> 4)) ^ (c & 7);
        bfr[nt] = *(const s16x8*)((const char*)Bs + c * 128 + ch * 16);
      }
      int r = wm * 16 + (lane & 15);
      int c0 = kk * 8 + (lane >> 4) * 2;
      f32x4 f0 = *(const f32x4*)((const char*)As + r * 256 + ((c0 ^ (r & 7)) * 16));
      f32x4 f1 = *(const f32x4*)((const char*)As + r * 256 + (((c0 + 1) ^ (r & 7)) * 16));
      s16x8 af;
#pragma unroll
      for (int t = 0; t < 4; t++) {
        af[t]     = (short)f2bf(f0[t]);
        af[t + 4] = (short)f2bf(f1[t]);
      }
#pragma unroll
      for (int nt = 0; nt < 4; nt++)
        acc[nt] = __builtin_amdgcn_mfma_f32_16x16x32_bf16(af, bfr[nt], acc[nt], 0, 0, 0);
    }
  }
  {
    int rb = rbase + wm * 16 + (lane >> 4) * 4;
#pragma unroll
    for (int j = 0; j < 4; j++) {
      int r = rb + j;
      bool ok = (r < NN);
#pragma unroll
      for (int nt = 0; nt < 4; nt++) {
        int c = wn * 64 + nt * 16 + (lane & 15);
        xb[(size_t)r * HC + c] = ok ? f2bf(acc[nt][j]) : (ushort)0;
      }
    }
  }
}

// Fused (R24 structure): chain role (196 blocks, 4096 edges, 16-deep ILP) with
// COARSE buckets: 98 regions of 512 nodes -> 19K cursor claims total (6x fewer
// hot-line RMWs than 782 buckets), ~42 entries/claim = multi-line-dense runs.
__launch_bounds__(256, 6)
__global__ void k_bg(const float* __restrict__ feats, const ushort* __restrict__ Wt,
                     ushort* __restrict__ xb, const int* __restrict__ ei,
                     int* __restrict__ bcur, unsigned* __restrict__ region,
                     unsigned char* __restrict__ mask) {
  __shared__ __align__(16) char smem[24576];
  bool chain; int cid, gid;
  role_map(blockIdx.x, 25, &chain, &cid, &gid);   // 200 chain slots, 196 used
  if (chain) {
    if (cid >= NCH) return;
    int* lcnt  = (int*)smem;                      // [NBKC]
    int* gb    = (int*)smem + NBKC;               // [NBKC]
    int* lcnt2 = (int*)smem + 2 * NBKC;           // [NBKC]
    const int tid = threadIdx.x;
    if (tid < NBKC) { lcnt[tid] = 0; lcnt2[tid] = 0; }
    __syncthreads();
    const int e0 = cid * EPB + tid;
    int dc[16];                                   // 16 independent loads (ILP)
#pragma unroll
    for (int k = 0; k < 16; k++) {
      int e = e0 + k * 256;
      dc[k] = (e < NE) ? ei[NE + e] : -1;
    }
#pragma unroll
    for (int k = 0; k < 16; k++)
      if (dc[k] >= 0) atomicAdd(&lcnt[dc[k] >> 9], 1);
    __syncthreads();
    if (tid < NBKC && lcnt[tid]) gb[tid] = atomicAdd(&bcur[tid], lcnt[tid]);
    __syncthreads();
    int sc[16];                                   // src reload (L2-hot)
#pragma unroll
    for (int k = 0; k < 16; k++) {
      int e = e0 + k * 256;
      sc[k] = (e < NE) ? ei[e] : -1;
    }
#pragma unroll
    for (int k = 0; k < 16; k++) {
      if (dc[k] >= 0) {
        int bkt = dc[k] >> 9;
        int r = atomicAdd(&lcnt2[bkt], 1);
        int p = gb[bkt] + r;
        if (p < BCAPC)
          region[(size_t)bkt * BCAPC + p] = ((unsigned)dc[k] << 16) | (unsigned)sc[k];
      }
    }
    return;
  }
  if (gid < 1563) gemm_tile(gid, feats, Wt, xb, mask, smem);
}

// region -> per-node csr16 + degrees. One block per coarse bucket (1024 thr):
// 512 LDS slot counters, block-exclusive 32 KB csr16 window.
__global__ void k_csr(const unsigned* __restrict__ region, const int* __restrict__ bcur,
                      ushort* __restrict__ csr16, int* __restrict__ slots) {
  __shared__ int lc[512];
  const int bkt = blockIdx.x;               // 0..97
  const int tid = threadIdx.x;              // 1024 threads
  if (tid < 512) lc[tid] = 0;
  __syncthreads();
  int cnt = bcur[bkt]; if (cnt > BCAPC) cnt = BCAPC;
  for (int i = tid; i < cnt; i += 1024) {
    unsigned u = region[(size_t)bkt * BCAPC + i];
    int d = u >> 16, s = u & 0xFFFFu;
    int slot = atomicAdd(&lc[d & 511], 1);
    if (slot < MAXDEG) csr16[(size_t)d * MAXDEG + slot] = (ushort)s;
  }
  __syncthreads();
  if (tid < 512) {
    int n = bkt * 512 + tid;
    if (n < NN) slots[n] = lc[tid];         // true degree
  }
}

// one wave per node, 4-way edge split, direct csr16 (R17-verified body):
// sum of x[src]*dinv[src], dinv f32 from L2-hot slots[]; dn+bias+relu+mask
// after reduce. Sentinel row NN (zeros), slots[NN]=0.
__global__ void k_agg(const ushort* __restrict__ xb, const int* __restrict__ slots,
                      const ushort* __restrict__ csr16,
                      const unsigned char* __restrict__ mask,
                      const float* __restrict__ b, float* __restrict__ out) {
  int n = blockIdx.x * 4 + (threadIdx.x >> 6);
  if (n >= NN) return;
  const int lane = threadIdx.x & 63;
  const int grp = lane >> 4;          // edge slot (0..3)
  const int q = lane & 15;            // channels q*8 .. q*8+7
  const int degt = slots[n];          // true degree
  const int deg = (degt < MAXDEG) ? degt : MAXDEG;
  const float dn = rsqrtf((float)(degt + 1));

  float a0, a1, a2, a3, a4, a5, a6, a7;
  {
    uint4 sv = *(const uint4*)(xb + (size_t)n * HC + q * 8);
    float z = (grp == 0) ? dn : 0.0f; // self term in group 0 (final *dn -> dn^2)
    a0 = __uint_as_float(sv.x << 16)         * z;
    a1 = __uint_as_float(sv.x & 0xFFFF0000u) * z;
    a2 = __uint_as_float(sv.y << 16)         * z;
    a3 = __uint_as_float(sv.y & 0xFFFF0000u) * z;
    a4 = __uint_as_float(sv.z << 16)         * z;
    a5 = __uint_as_float(sv.z & 0xFFFF0000u) * z;
    a6 = __uint_as_float(sv.w << 16)         * z;
    a7 = __uint_as_float(sv.w & 0xFFFF0000u) * z;
  }

  const ushort* cp = csr16 + (size_t)n * MAXDEG;
  const int np = (deg + 3) >> 2;      // quads
  unsigned s0 = (grp < deg) ? cp[grp] : (unsigned)NN;   // sentinel = zero row
  uint4 g = *(const uint4*)(xb + (size_t)s0 * HC + q * 8);
  int c0 = slots[s0];
  for (int j = 0; j < np; ++j) {
    int idx = 4 * j + 4 + grp;
    unsigned s1 = (idx < deg) ? cp[idx] : (unsigned)NN;
    uint4 gn = *(const uint4*)(xb + (size_t)s1 * HC + q * 8);
    int c1 = slots[s1];
    float di = rsqrtf((float)(c0 + 1));   // dinv[src], f32 precision
    a0 += __uint_as_float(g.x << 16)         * di;
    a1 += __uint_as_float(g.x & 0xFFFF0000u) * di;
    a2 += __uint_as_float(g.y << 16)         * di;
    a3 += __uint_as_float(g.y & 0xFFFF0000u) * di;
    a4 += __uint_as_float(g.z << 16)         * di;
    a5 += __uint_as_float(g.z & 0xFFFF0000u) * di;
    a6 += __uint_as_float(g.w << 16)         * di;
    a7 += __uint_as_float(g.w & 0xFFFF0000u) * di;
    g = gn; c0 = c1;
  }
#define RED(A) A += __shfl_xor(A, 16); A += __shfl_xor(A, 32);
  RED(a0) RED(a1) RED(a2) RED(a3) RED(a4) RED(a5) RED(a6) RED(a7)
#undef RED
  float sx = (grp == 0) ? a0 : (grp == 1) ? a2 : (grp == 2) ? a4 : a6;
  float sy = (grp == 0) ? a1 : (grp == 1) ? a3 : (grp == 2) ? a5 : a7;
  int i0 = n * HC + q * 8 + 2 * grp;
  f32x2 bb = *(const f32x2*)(b + q * 8 + 2 * grp);
  float vx = fmaxf(sx * dn + bb.x, 0.f) * 2.f;
  float vy = fmaxf(sy * dn + bb.y, 0.f) * 2.f;
  unsigned m = mask[n * 16 + q];      // drop bits for elements q*8 .. q*8+7
  f32x2 r;
  r.x = ((m >> (2 * grp))     & 1u) ? 0.f : vx;
  r.y = ((m >> (2 * grp + 1)) & 1u) ? 0.f : vy;
  *(f32x2*)(out + i0) = r;
}

extern "C" void kernel_launch(void* const* d_in, const int* in_sizes, int n_in,
                              void* d_out, int out_size, void* d_ws, size_t ws_size,
                              hipStream_t stream) {
  const float* feats = (const float*)d_in[0];
  const float* W     = (const float*)d_in[1];
  const float* b     = (const float*)d_in[2];
  const int*   ei    = (const int*)d_in[3];
  float* out = (float*)d_out;

  // ws: xb[50016*HC] bf16 | Wt[HC*KIN] bf16 | slots[NN+1] i32 | mask[NE+512] u8
  //   | bcur[NBKC] i32 | csr16[NN*64] u16 | region[NBKC*BCAPC] u32   (~25 MB)
  char* ws = (char*)d_ws;
  size_t o = 0;
  ushort*        xb     = (ushort*)(ws + o);        o += ((size_t)50016 * HC * 2 + 255) & ~(size_t)255;
  ushort*        Wt     = (ushort*)(ws + o);        o += ((size_t)HC * KIN * 2 + 255) & ~(size_t)255;
  int*           slots  = (int*)(ws + o);           o += ((size_t)(NN + 1) * 4 + 255) & ~(size_t)255;
  unsigned char* mask   = (unsigned char*)(ws + o); o += ((size_t)NE + 512 + 255) & ~(size_t)255;
  int*           bcur   = (int*)(ws + o);           o += ((size_t)NBKC * 4 + 255) & ~(size_t)255;
  ushort*        csr16  = (ushort*)(ws + o);        o += ((size_t)NN * MAXDEG * 2 + 255) & ~(size_t)255;
  unsigned*      region = (unsigned*)(ws + o);

  k_prep<<<256, 256, 0, stream>>>(W, Wt, slots, bcur);
  k_bg  <<<1763, 256, 0, stream>>>(feats, Wt, xb, ei, bcur, region, mask);
  k_csr <<<NBKC, 1024, 0, stream>>>(region, bcur, csr16, slots);
  k_agg <<<(NN + 3) / 4, 256, 0, stream>>>(xb, slots, csr16, mask, b, out);
}

// Round 27
// 83.399 us; speedup vs baseline: 1.1226x; 1.0194x over previous
//
#include <hip/hip_runtime.h>

#define NN 50000
#define NE 800000
#define KIN 512
#define HC 128
#define MAXDEG 64
#define NBK 782                      // dst buckets of 64 nodes
#define BCAP 1536                    // bucket region capacity (max sum ~1140)
#define EPB 4096                     // edges per chain block
#define NCH 196                      // chain blocks (196*4096 >= NE)

typedef float f32x4 __attribute__((ext_vector_type(4)));
typedef float f32x2 __attribute__((ext_vector_type(2)));
typedef short s16x8 __attribute__((ext_vector_type(8)));

__device__ __forceinline__ ushort f2bf(float f) {
  unsigned u = __float_as_uint(f);
  unsigned r = (u + 0x7FFFu + ((u >> 16) & 1u)) >> 16;  // RNE
  return (ushort)r;
}

__device__ __forceinline__ void gload_lds16(const void* g, void* l) {
  __builtin_amdgcn_global_load_lds((const __attribute__((address_space(1))) void*)g,
                                   (__attribute__((address_space(3))) void*)l, 16, 0, 0);
}

// JAX threefry2x32-20, partitionable path: ctr=(0,i), key=(0,42), bits=o0^o1
__device__ __forceinline__ unsigned tf_bits(unsigned i) {
  unsigned x0 = 0u, x1 = i;
  const unsigned ks0 = 0u, ks1 = 42u, ks2 = 0x1BD11BDAu ^ 42u;
#define R(r) { x0 += x1; x1 = (x1 << r) | (x1 >> (32 - r)); x1 ^= x0; }
  x0 += ks0; x1 += ks1;
  R(13) R(15) R(26) R(6)
  x0 += ks1; x1 += ks2 + 1u;
  R(17) R(29) R(16) R(24)
  x0 += ks2; x1 += ks0 + 2u;
  R(13) R(15) R(26) R(6)
  x0 += ks0; x1 += ks1 + 3u;
  R(17) R(29) R(16) R(24)
  x0 += ks1; x1 += ks2 + 4u;
  R(13) R(15) R(26) R(6)
  x0 += ks2; x1 += ks0 + 5u;
#undef R
  return x0 ^ x1;
}

// role map (R20-verified): 8-aligned groups alternate chain/task for first
// 2*nchg groups (spreads roles across XCDs under bid%8 dispatch), then task.
__device__ __forceinline__ void role_map(int bid, int nchg, bool* chain,
                                         int* cid, int* gid) {
  int g8 = bid >> 3, sub = bid & 7;
  if (g8 < 2 * nchg) {
    *chain = ((g8 & 1) == 0);
    int h = g8 >> 1;
    *cid = h * 8 + sub;
    *gid = h * 8 + sub;
  } else {
    *chain = false; *cid = 0;
    *gid = nchg * 8 + (g8 - 2 * nchg) * 8 + sub;
  }
}

// Wt transpose/convert + zero cursors + sentinel slots[NN]=0
__global__ void k_prep(const float* __restrict__ W, ushort* __restrict__ Wt,
                       int* __restrict__ slots, int* __restrict__ bcur) {
  int t = blockIdx.x * 256 + threadIdx.x;   // 65536 threads
  if (t < NBK) bcur[t] = 0;
  if (t == NBK) slots[NN] = 0;              // sentinel (rest set by k_csr)
  if (t < KIN * HC) {
    int c = t & (HC - 1), k = t >> 7;       // W row-major [k][c]
    Wt[c * KIN + k] = f2bf(W[t]);
  }
}

// GEMM tile body (R22-verified): xb = feats @ W unscaled bf16 (rows>=NN zero
// sentinel) + dropout-mask bytes. smem: [0,8K)=As, [8K,24K)=Bs.
__device__ void gemm_tile(int g, const float* __restrict__ feats,
                          const ushort* __restrict__ Wt, ushort* __restrict__ xb,
                          unsigned char* __restrict__ mask, char* smem) {
  float*  As = (float*)smem;                      // 32x64 f32, 256 B/row
  ushort* Bs = (ushort*)(smem + 8192);            // 128x64 bf16, 128 B/row
  const int tid = threadIdx.x;
  const int lane = tid & 63;
  const int w = tid >> 6;
  const int wm = w >> 1, wn = w & 1;
  const int rbase = g * 32;                       // rows 0..50015

  {
    int mb = rbase * 16 + tid;
#pragma unroll
    for (int h = 0; h < 2; ++h, mb += 256) {
      if (mb < NN * 16) {
        unsigned by = 0;
#pragma unroll
        for (int k = 0; k < 8; k++)
          by |= (tf_bits(8u * (unsigned)mb + k) >> 31) << k;   // bit=1 -> drop
        mask[mb] = (unsigned char)by;
      }
    }
  }

  f32x4 acc[4];
#pragma unroll
  for (int nt = 0; nt < 4; nt++) acc[nt] = f32x4{0.f, 0.f, 0.f, 0.f};

  const int a_rt = w * 8 + (lane >> 4);
  int a_gr[2];
#pragma unroll
  for (int i = 0; i < 2; i++) {
    int gr = rbase + a_rt + i * 4;
    a_gr[i] = (gr < NN) ? gr : NN - 1;
  }
  const int b_ct = w * 32 + (lane >> 3);              // + i*8 ; B tile col (Wt row)
  const int b_ch = ((lane & 7) ^ (b_ct & 7)) << 3;    // bf16 offset of swizzled chunk

  for (int ks = 0; ks < KIN; ks += 64) {
    __syncthreads();                               // prev-step LDS reads done
#pragma unroll
    for (int i = 0; i < 2; i++) {
      // A dest row ar = a_rt + i*4 -> (ar&7) = (a_rt&7) ^ ((i&1)<<2)
      int a_ch = ((lane & 15) ^ (a_rt & 7) ^ ((i & 1) << 2)) << 2;   // f32 offset
      gload_lds16(feats + (size_t)a_gr[i] * KIN + ks + a_ch,
                  (char*)As + (w * 8 + i * 4) * 256);
    }
#pragma unroll
    for (int i = 0; i < 4; i++)
      gload_lds16(Wt + (size_t)(b_ct + i * 8) * KIN + ks + b_ch,
                  (char*)Bs + (w * 32 + i * 8) * 128);
    __syncthreads();                               // staged (vmcnt drained by barrier)
#pragma unroll
    for (int kk = 0; kk < 2; kk++) {
      s16x8 bfr[4];
#pragma unroll
      for (int nt = 0; nt < 4; nt++) {
        int c = wn * 64 + nt * 16 + (lane & 15);
        int ch = (kk * 4 + (lane >> 4)) ^ (c & 7);
        bfr[nt] = *(const s16x8*)((const char*)Bs + c * 128 + ch * 16);
      }
      int r = wm * 16 + (lane & 15);
      int c0 = kk * 8 + (lane >> 4) * 2;
      f32x4 f0 = *(const f32x4*)((const char*)As + r * 256 + ((c0 ^ (r & 7)) * 16));
      f32x4 f1 = *(const f32x4*)((const char*)As + r * 256 + (((c0 + 1) ^ (r & 7)) * 16));
      s16x8 af;
#pragma unroll
      for (int t = 0; t < 4; t++) {
        af[t]     = (short)f2bf(f0[t]);
        af[t + 4] = (short)f2bf(f1[t]);
      }
#pragma unroll
      for (int nt = 0; nt < 4; nt++)
        acc[nt] = __builtin_amdgcn_mfma_f32_16x16x32_bf16(af, bfr[nt], acc[nt], 0, 0, 0);
    }
  }
  {
    int rb = rbase + wm * 16 + (lane >> 4) * 4;
#pragma unroll
    for (int j = 0; j < 4; j++) {
      int r = rb + j;
      bool ok = (r < NN);
#pragma unroll
      for (int nt = 0; nt < 4; nt++) {
        int c = wn * 64 + nt * 16 + (lane & 15);
        xb[(size_t)r * HC + c] = ok ? f2bf(acc[nt][j]) : (ushort)0;
      }
    }
  }
}

// Fused (R24 structure): chain role = ONE-PASS sort (R19 k_sort insight:
// the histogram atomicAdd IS the rank) -> half the LDS-atomic traffic of
// R24's two-pass body. gemm role unchanged.
__launch_bounds__(256, 6)
__global__ void k_bg(const float* __restrict__ feats, const ushort* __restrict__ Wt,
                     ushort* __restrict__ xb, const int* __restrict__ ei,
                     int* __restrict__ bcur, unsigned* __restrict__ region,
                     unsigned char* __restrict__ mask) {
  __shared__ __align__(16) char smem[24576];
  bool chain; int cid, gid;
  role_map(blockIdx.x, 25, &chain, &cid, &gid);   // 200 chain slots, 196 used
  if (chain) {
    if (cid >= NCH) return;
    int* lcnt = (int*)smem;                       // [NBK]
    int* gb   = (int*)smem + NBK;                 // [NBK]
    const int tid = threadIdx.x;
    for (int i = tid; i < NBK; i += 256) lcnt[i] = 0;
    __syncthreads();
    const int e0 = cid * EPB + tid;
    int dc[16], lr[16];                           // 16-deep ILP; rank from hist
#pragma unroll
    for (int k = 0; k < 16; k++) {
      int e = e0 + k * 256;
      dc[k] = (e < NE) ? ei[NE + e] : -1;
    }
#pragma unroll
    for (int k = 0; k < 16; k++)
      if (dc[k] >= 0) lr[k] = atomicAdd(&lcnt[dc[k] >> 6], 1);   // rank + count
    __syncthreads();
    for (int i = tid; i < NBK; i += 256)
      if (lcnt[i]) gb[i] = atomicAdd(&bcur[i], lcnt[i]);  // batched claim
    __syncthreads();
    int sc[16];                                   // src reload (L2-hot)
#pragma unroll
    for (int k = 0; k < 16; k++) {
      int e = e0 + k * 256;
      sc[k] = (e < NE) ? ei[e] : -1;
    }
#pragma unroll
    for (int k = 0; k < 16; k++) {
      if (dc[k] >= 0) {
        int bkt = dc[k] >> 6;
        int p = gb[bkt] + lr[k];
        if (p < BCAP)
          region[(size_t)bkt * BCAP + p] = ((unsigned)dc[k] << 16) | (unsigned)sc[k];
      }
    }
    return;
  }
  if (gid < 1563) gemm_tile(gid, feats, Wt, xb, mask, smem);
}

// region -> per-node csr16 + degrees. One block per bucket: LDS slot counters,
// block-exclusive 8 KB csr16 window -> burst-dense stores. (R19-verified body)
__global__ void k_csr(const unsigned* __restrict__ region, const int* __restrict__ bcur,
                      ushort* __restrict__ csr16, int* __restrict__ slots) {
  __shared__ int lc[64];
  const int bkt = blockIdx.x;               // 0..781
  const int tid = threadIdx.x;
  if (tid < 64) lc[tid] = 0;
  __syncthreads();
  int cnt = bcur[bkt]; if (cnt > BCAP) cnt = BCAP;
  for (int i = tid; i < cnt; i += 256) {
    unsigned u = region[(size_t)bkt * BCAP + i];
    int d = u >> 16, s = u & 0xFFFFu;
    int slot = atomicAdd(&lc[d & 63], 1);
    if (slot < MAXDEG) csr16[(size_t)d * MAXDEG + slot] = (ushort)s;
  }
  __syncthreads();
  if (tid < 64) {
    int n = bkt * 64 + tid;
    if (n < NN) slots[n] = lc[tid];         // true degree
  }
}

// one wave per node, 4-way edge split, direct csr16 (R17-verified body):
// sum of x[src]*dinv[src], dinv f32 from L2-hot slots[]; dn+bias+relu+mask
// after reduce. Sentinel row NN (zeros), slots[NN]=0.
__global__ void k_agg(const ushort* __restrict__ xb, const int* __restrict__ slots,
                      const ushort* __restrict__ csr16,
                      const unsigned char* __restrict__ mask,
                      const float* __restrict__ b, float* __restrict__ out) {
  int n = blockIdx.x * 4 + (threadIdx.x >> 6);
  if (n >= NN) return;
  const int lane = threadIdx.x & 63;
  const int grp = lane >> 4;          // edge slot (0..3)
  const int q = lane & 15;            // channels q*8 .. q*8+7
  const int degt = slots[n];          // true degree
  const int deg = (degt < MAXDEG) ? degt : MAXDEG;
  const float dn = rsqrtf((float)(degt + 1));

  float a0, a1, a2, a3, a4, a5, a6, a7;
  {
    uint4 sv = *(const uint4*)(xb + (size_t)n * HC + q * 8);
    float z = (grp == 0) ? dn : 0.0f; // self term in group 0 (final *dn -> dn^2)
    a0 = __uint_as_float(sv.x << 16)         * z;
    a1 = __uint_as_float(sv.x & 0xFFFF0000u) * z;
    a2 = __uint_as_float(sv.y << 16)         * z;
    a3 = __uint_as_float(sv.y & 0xFFFF0000u) * z;
    a4 = __uint_as_float(sv.z << 16)         * z;
    a5 = __uint_as_float(sv.z & 0xFFFF0000u) * z;
    a6 = __uint_as_float(sv.w << 16)         * z;
    a7 = __uint_as_float(sv.w & 0xFFFF0000u) * z;
  }

  const ushort* cp = csr16 + (size_t)n * MAXDEG;
  const int np = (deg + 3) >> 2;      // quads
  unsigned s0 = (grp < deg) ? cp[grp] : (unsigned)NN;   // sentinel = zero row
  uint4 g = *(const uint4*)(xb + (size_t)s0 * HC + q * 8);
  int c0 = slots[s0];
  for (int j = 0; j < np; ++j) {
    int idx = 4 * j + 4 + grp;
    unsigned s1 = (idx < deg) ? cp[idx] : (unsigned)NN;
    uint4 gn = *(const uint4*)(xb + (size_t)s1 * HC + q * 8);
    int c1 = slots[s1];
    float di = rsqrtf((float)(c0 + 1));   // dinv[src], f32 precision
    a0 += __uint_as_float(g.x << 16)         * di;
    a1 += __uint_as_float(g.x & 0xFFFF0000u) * di;
    a2 += __uint_as_float(g.y << 16)         * di;
    a3 += __uint_as_float(g.y & 0xFFFF0000u) * di;
    a4 += __uint_as_float(g.z << 16)         * di;
    a5 += __uint_as_float(g.z & 0xFFFF0000u) * di;
    a6 += __uint_as_float(g.w << 16)         * di;
    a7 += __uint_as_float(g.w & 0xFFFF0000u) * di;
    g = gn; c0 = c1;
  }
#define RED(A) A += __shfl_xor(A, 16); A += __shfl_xor(A, 32);
  RED(a0) RED(a1) RED(a2) RED(a3) RED(a4) RED(a5) RED(a6) RED(a7)
#undef RED
  float sx = (grp == 0) ? a0 : (grp == 1) ? a2 : (grp == 2) ? a4 : a6;
  float sy = (grp == 0) ? a1 : (grp == 1) ? a3 : (grp == 2) ? a5 : a7;
  int i0 = n * HC + q * 8 + 2 * grp;
  f32x2 bb = *(const f32x2*)(b + q * 8 + 2 * grp);
  float vx = fmaxf(sx * dn + bb.x, 0.f) * 2.f;
  float vy = fmaxf(sy * dn + bb.y, 0.f) * 2.f;
  unsigned m = mask[n * 16 + q];      // drop bits for elements q*8 .. q*8+7
  f32x2 r;
  r.x = ((m >> (2 * grp))     & 1u) ? 0.f : vx;
  r.y = ((m >> (2 * grp + 1)) & 1u) ? 0.f : vy;
  *(f32x2*)(out + i0) = r;
}

extern "C" void kernel_launch(void* const* d_in, const int* in_sizes, int n_in,
                              void* d_out, int out_size, void* d_ws, size_t ws_size,
                              hipStream_t stream) {
  const float* feats = (const float*)d_in[0];
  const float* W     = (const float*)d_in[1];
  const float* b     = (const float*)d_in[2];
  const int*   ei    = (const int*)d_in[3];
  float* out = (float*)d_out;

  // ws: xb[50016*HC] bf16 | Wt[HC*KIN] bf16 | slots[NN+1] i32 | mask[NE+512] u8
  //   | bcur[NBK] i32 | csr16[NN*64] u16 | region[NBK*BCAP] u32   (~25 MB)
  char* ws = (char*)d_ws;
  size_t o = 0;
  ushort*        xb     = (ushort*)(ws + o);        o += ((size_t)50016 * HC * 2 + 255) & ~(size_t)255;
  ushort*        Wt     = (ushort*)(ws + o);        o += ((size_t)HC * KIN * 2 + 255) & ~(size_t)255;
  int*           slots  = (int*)(ws + o);           o += ((size_t)(NN + 1) * 4 + 255) & ~(size_t)255;
  unsigned char* mask   = (unsigned char*)(ws + o); o += ((size_t)NE + 512 + 255) & ~(size_t)255;
  int*           bcur   = (int*)(ws + o);           o += ((size_t)NBK * 4 + 255) & ~(size_t)255;
  ushort*        csr16  = (ushort*)(ws + o);        o += ((size_t)NN * MAXDEG * 2 + 255) & ~(size_t)255;
  unsigned*      region = (unsigned*)(ws + o);

  k_prep<<<256, 256, 0, stream>>>(W, Wt, slots, bcur);
  k_bg  <<<1763, 256, 0, stream>>>(feats, Wt, xb, ei, bcur, region, mask);
  k_csr <<<NBK, 256, 0, stream>>>(region, bcur, csr16, slots);
  k_agg <<<(NN + 3) / 4, 256, 0, stream>>>(xb, slots, csr16, mask, b, out);
}

// Round 28
// 81.529 us; speedup vs baseline: 1.1484x; 1.0229x over previous
//
#include <hip/hip_runtime.h>

#define NN 50000
#define NE 800000
#define KIN 512
#define HC 128
#define MAXDEG 64
#define NBK 782                      // dst buckets of 64 nodes
#define BCAP 1536                    // bucket region capacity (max sum ~1140)
#define EPB 4096                     // edges per chain block
#define NCH 196                      // chain blocks (196*4096 >= NE)

typedef float f32x4 __attribute__((ext_vector_type(4)));
typedef float f32x2 __attribute__((ext_vector_type(2)));
typedef short s16x8 __attribute__((ext_vector_type(8)));

__device__ __forceinline__ ushort f2bf(float f) {
  unsigned u = __float_as_uint(f);
  unsigned r = (u + 0x7FFFu + ((u >> 16) & 1u)) >> 16;  // RNE
  return (ushort)r;
}

__device__ __forceinline__ void gload_lds16(const void* g, void* l) {
  __builtin_amdgcn_global_load_lds((const __attribute__((address_space(1))) void*)g,
                                   (__attribute__((address_space(3))) void*)l, 16, 0, 0);
}

// JAX threefry2x32-20, partitionable path: ctr=(0,i), key=(0,42), bits=o0^o1
__device__ __forceinline__ unsigned tf_bits(unsigned i) {
  unsigned x0 = 0u, x1 = i;
  const unsigned ks0 = 0u, ks1 = 42u, ks2 = 0x1BD11BDAu ^ 42u;
#define R(r) { x0 += x1; x1 = (x1 << r) | (x1 >> (32 - r)); x1 ^= x0; }
  x0 += ks0; x1 += ks1;
  R(13) R(15) R(26) R(6)
  x0 += ks1; x1 += ks2 + 1u;
  R(17) R(29) R(16) R(24)
  x0 += ks2; x1 += ks0 + 2u;
  R(13) R(15) R(26) R(6)
  x0 += ks0; x1 += ks1 + 3u;
  R(17) R(29) R(16) R(24)
  x0 += ks1; x1 += ks2 + 4u;
  R(13) R(15) R(26) R(6)
  x0 += ks2; x1 += ks0 + 5u;
#undef R
  return x0 ^ x1;
}

// role map (R20-verified): 8-aligned groups alternate chain/task for first
// 2*nchg groups (spreads roles across XCDs under bid%8 dispatch), then task.
__device__ __forceinline__ void role_map(int bid, int nchg, bool* chain,
                                         int* cid, int* gid) {
  int g8 = bid >> 3, sub = bid & 7;
  if (g8 < 2 * nchg) {
    *chain = ((g8 & 1) == 0);
    int h = g8 >> 1;
    *cid = h * 8 + sub;
    *gid = h * 8 + sub;
  } else {
    *chain = false; *cid = 0;
    *gid = nchg * 8 + (g8 - 2 * nchg) * 8 + sub;
  }
}

// Wt transpose/convert + zero cursors + sentinel slots[NN]=0
__global__ void k_prep(const float* __restrict__ W, ushort* __restrict__ Wt,
                       int* __restrict__ slots, int* __restrict__ bcur) {
  int t = blockIdx.x * 256 + threadIdx.x;   // 65536 threads
  if (t < NBK) bcur[t] = 0;
  if (t == NBK) slots[NN] = 0;              // sentinel (rest set by k_csr)
  if (t < KIN * HC) {
    int c = t & (HC - 1), k = t >> 7;       // W row-major [k][c]
    Wt[c * KIN + k] = f2bf(W[t]);
  }
}

// GEMM tile body (R22-verified): xb = feats @ W unscaled bf16 (rows>=NN zero
// sentinel) + dropout-mask bytes. smem: [0,8K)=As, [8K,24K)=Bs.
__device__ void gemm_tile(int g, const float* __restrict__ feats,
                          const ushort* __restrict__ Wt, ushort* __restrict__ xb,
                          unsigned char* __restrict__ mask, char* smem) {
  float*  As = (float*)smem;                      // 32x64 f32, 256 B/row
  ushort* Bs = (ushort*)(smem + 8192);            // 128x64 bf16, 128 B/row
  const int tid = threadIdx.x;
  const int lane = tid & 63;
  const int w = tid >> 6;
  const int wm = w >> 1, wn = w & 1;
  const int rbase = g * 32;                       // rows 0..50015

  {
    int mb = rbase * 16 + tid;
#pragma unroll
    for (int h = 0; h < 2; ++h, mb += 256) {
      if (mb < NN * 16) {
        unsigned by = 0;
#pragma unroll
        for (int k = 0; k < 8; k++)
          by |= (tf_bits(8u * (unsigned)mb + k) >> 31) << k;   // bit=1 -> drop
        mask[mb] = (unsigned char)by;
      }
    }
  }

  f32x4 acc[4];
#pragma unroll
  for (int nt = 0; nt < 4; nt++) acc[nt] = f32x4{0.f, 0.f, 0.f, 0.f};

  const int a_rt = w * 8 + (lane >> 4);
  int a_gr[2];
#pragma unroll
  for (int i = 0; i < 2; i++) {
    int gr = rbase + a_rt + i * 4;
    a_gr[i] = (gr < NN) ? gr : NN - 1;
  }
  const int b_ct = w * 32 + (lane >> 3);              // + i*8 ; B tile col (Wt row)
  const int b_ch = ((lane & 7) ^ (b_ct & 7)) << 3;    // bf16 offset of swizzled chunk

  for (int ks = 0; ks < KIN; ks += 64) {
    __syncthreads();                               // prev-step LDS reads done
#pragma unroll
    for (int i = 0; i < 2; i++) {
      // A dest row ar = a_rt + i*4 -> (ar&7) = (a_rt&7) ^ ((i&1)<<2)
      int a_ch = ((lane & 15) ^ (a_rt & 7) ^ ((i & 1) << 2)) << 2;   // f32 offset
      gload_lds16(feats + (size_t)a_gr[i] * KIN + ks + a_ch,
                  (char*)As + (w * 8 + i * 4) * 256);
    }
#pragma unroll
    for (int i = 0; i < 4; i++)
      gload_lds16(Wt + (size_t)(b_ct + i * 8) * KIN + ks + b_ch,
                  (char*)Bs + (w * 32 + i * 8) * 128);
    __syncthreads();                               // staged (vmcnt drained by barrier)
#pragma unroll
    for (int kk = 0; kk < 2; kk++) {
      s16x8 bfr[4];
#pragma unroll
      for (int nt = 0; nt < 4; nt++) {
        int c = wn * 64 + nt * 16 + (lane & 15);
        int ch = (kk * 4 + (lane >> 4)) ^ (c & 7);
        bfr[nt] = *(const s16x8*)((const char*)Bs + c * 128 + ch * 16);
      }
      int r = wm * 16 + (lane & 15);
      int c0 = kk * 8 + (lane >> 4) * 2;
      f32x4 f0 = *(const f32x4*)((const char*)As + r * 256 + ((c0 ^ (r & 7)) * 16));
      f32x4 f1 = *(const f32x4*)((const char*)As + r * 256 + (((c0 + 1) ^ (r & 7)) * 16));
      s16x8 af;
#pragma unroll
      for (int t = 0; t < 4; t++) {
        af[t]     = (short)f2bf(f0[t]);
        af[t + 4] = (short)f2bf(f1[t]);
      }
#pragma unroll
      for (int nt = 0; nt < 4; nt++)
        acc[nt] = __builtin_amdgcn_mfma_f32_16x16x32_bf16(af, bfr[nt], acc[nt], 0, 0, 0);
    }
  }
  {
    int rb = rbase + wm * 16 + (lane >> 4) * 4;
#pragma unroll
    for (int j = 0; j < 4; j++) {
      int r = rb + j;
      bool ok = (r < NN);
#pragma unroll
      for (int nt = 0; nt < 4; nt++) {
        int c = wn * 64 + nt * 16 + (lane & 15);
        xb[(size_t)r * HC + c] = ok ? f2bf(acc[nt][j]) : (ushort)0;
      }
    }
  }
}

// Fused (R24-verified, best config): chain role (196 blocks, 4096 edges each,
// 16-deep reg ILP): two-pass LDS-batched scatter, one cursor claim per touched
// bucket per block, finishes inside the gemm phase (no tail).
__launch_bounds__(256, 6)
__global__ void k_bg(const float* __restrict__ feats, const ushort* __restrict__ Wt,
                     ushort* __restrict__ xb, const int* __restrict__ ei,
                     int* __restrict__ bcur, unsigned* __restrict__ region,
                     unsigned char* __restrict__ mask) {
  __shared__ __align__(16) char smem[24576];
  bool chain; int cid, gid;
  role_map(blockIdx.x, 25, &chain, &cid, &gid);   // 200 chain slots, 196 used
  if (chain) {
    if (cid >= NCH) return;
    int* lcnt  = (int*)smem;                      // [NBK]
    int* gb    = (int*)smem + NBK;                // [NBK]
    int* lcnt2 = (int*)smem + 2 * NBK;            // [NBK]
    const int tid = threadIdx.x;
    for (int i = tid; i < NBK; i += 256) { lcnt[i] = 0; lcnt2[i] = 0; }
    __syncthreads();
    const int e0 = cid * EPB + tid;
    int dc[16];                                   // 16 independent loads (ILP)
#pragma unroll
    for (int k = 0; k < 16; k++) {
      int e = e0 + k * 256;
      dc[k] = (e < NE) ? ei[NE + e] : -1;
    }
#pragma unroll
    for (int k = 0; k < 16; k++)
      if (dc[k] >= 0) atomicAdd(&lcnt[dc[k] >> 6], 1);
    __syncthreads();
    for (int i = tid; i < NBK; i += 256)
      if (lcnt[i]) gb[i] = atomicAdd(&bcur[i], lcnt[i]);  // batched claim
    __syncthreads();
    int sc[16];                                   // src reload (L2-hot)
#pragma unroll
    for (int k = 0; k < 16; k++) {
      int e = e0 + k * 256;
      sc[k] = (e < NE) ? ei[e] : -1;
    }
#pragma unroll
    for (int k = 0; k < 16; k++) {
      if (dc[k] >= 0) {
        int bkt = dc[k] >> 6;
        int r = atomicAdd(&lcnt2[bkt], 1);
        int p = gb[bkt] + r;
        if (p < BCAP)
          region[(size_t)bkt * BCAP + p] = ((unsigned)dc[k] << 16) | (unsigned)sc[k];
      }
    }
    return;
  }
  if (gid < 1563) gemm_tile(gid, feats, Wt, xb, mask, smem);
}

// region -> per-node csr16 + degrees. One block per bucket: LDS slot counters,
// block-exclusive 8 KB csr16 window -> burst-dense stores. (R19-verified body)
__global__ void k_csr(const unsigned* __restrict__ region, const int* __restrict__ bcur,
                      ushort* __restrict__ csr16, int* __restrict__ slots) {
  __shared__ int lc[64];
  const int bkt = blockIdx.x;               // 0..781
  const int tid = threadIdx.x;
  if (tid < 64) lc[tid] = 0;
  __syncthreads();
  int cnt = bcur[bkt]; if (cnt > BCAP) cnt = BCAP;
  for (int i = tid; i < cnt; i += 256) {
    unsigned u = region[(size_t)bkt * BCAP + i];
    int d = u >> 16, s = u & 0xFFFFu;
    int slot = atomicAdd(&lc[d & 63], 1);
    if (slot < MAXDEG) csr16[(size_t)d * MAXDEG + slot] = (ushort)s;
  }
  __syncthreads();
  if (tid < 64) {
    int n = bkt * 64 + tid;
    if (n < NN) slots[n] = lc[tid];         // true degree
  }
}

// one wave per node, 4-way edge split, direct csr16 (R17-verified body):
// sum of x[src]*dinv[src], dinv f32 from L2-hot slots[]; dn+bias+relu+mask
// after reduce. Sentinel row NN (zeros), slots[NN]=0.
__global__ void k_agg(const ushort* __restrict__ xb, const int* __restrict__ slots,
                      const ushort* __restrict__ csr16,
                      const unsigned char* __restrict__ mask,
                      const float* __restrict__ b, float* __restrict__ out) {
  int n = blockIdx.x * 4 + (threadIdx.x >> 6);
  if (n >= NN) return;
  const int lane = threadIdx.x & 63;
  const int grp = lane >> 4;          // edge slot (0..3)
  const int q = lane & 15;            // channels q*8 .. q*8+7
  const int degt = slots[n];          // true degree
  const int deg = (degt < MAXDEG) ? degt : MAXDEG;
  const float dn = rsqrtf((float)(degt + 1));

  float a0, a1, a2, a3, a4, a5, a6, a7;
  {
    uint4 sv = *(const uint4*)(xb + (size_t)n * HC + q * 8);
    float z = (grp == 0) ? dn : 0.0f; // self term in group 0 (final *dn -> dn^2)
    a0 = __uint_as_float(sv.x << 16)         * z;
    a1 = __uint_as_float(sv.x & 0xFFFF0000u) * z;
    a2 = __uint_as_float(sv.y << 16)         * z;
    a3 = __uint_as_float(sv.y & 0xFFFF0000u) * z;
    a4 = __uint_as_float(sv.z << 16)         * z;
    a5 = __uint_as_float(sv.z & 0xFFFF0000u) * z;
    a6 = __uint_as_float(sv.w << 16)         * z;
    a7 = __uint_as_float(sv.w & 0xFFFF0000u) * z;
  }

  const ushort* cp = csr16 + (size_t)n * MAXDEG;
  const int np = (deg + 3) >> 2;      // quads
  unsigned s0 = (grp < deg) ? cp[grp] : (unsigned)NN;   // sentinel = zero row
  uint4 g = *(const uint4*)(xb + (size_t)s0 * HC + q * 8);
  int c0 = slots[s0];
  for (int j = 0; j < np; ++j) {
    int idx = 4 * j + 4 + grp;
    unsigned s1 = (idx < deg) ? cp[idx] : (unsigned)NN;
    uint4 gn = *(const uint4*)(xb + (size_t)s1 * HC + q * 8);
    int c1 = slots[s1];
    float di = rsqrtf((float)(c0 + 1));   // dinv[src], f32 precision
    a0 += __uint_as_float(g.x << 16)         * di;
    a1 += __uint_as_float(g.x & 0xFFFF0000u) * di;
    a2 += __uint_as_float(g.y << 16)         * di;
    a3 += __uint_as_float(g.y & 0xFFFF0000u) * di;
    a4 += __uint_as_float(g.z << 16)         * di;
    a5 += __uint_as_float(g.z & 0xFFFF0000u) * di;
    a6 += __uint_as_float(g.w << 16)         * di;
    a7 += __uint_as_float(g.w & 0xFFFF0000u) * di;
    g = gn; c0 = c1;
  }
#define RED(A) A += __shfl_xor(A, 16); A += __shfl_xor(A, 32);
  RED(a0) RED(a1) RED(a2) RED(a3) RED(a4) RED(a5) RED(a6) RED(a7)
#undef RED
  float sx = (grp == 0) ? a0 : (grp == 1) ? a2 : (grp == 2) ? a4 : a6;
  float sy = (grp == 0) ? a1 : (grp == 1) ? a3 : (grp == 2) ? a5 : a7;
  int i0 = n * HC + q * 8 + 2 * grp;
  f32x2 bb = *(const f32x2*)(b + q * 8 + 2 * grp);
  float vx = fmaxf(sx * dn + bb.x, 0.f) * 2.f;
  float vy = fmaxf(sy * dn + bb.y, 0.f) * 2.f;
  unsigned m = mask[n * 16 + q];      // drop bits for elements q*8 .. q*8+7
  f32x2 r;
  r.x = ((m >> (2 * grp))     & 1u) ? 0.f : vx;
  r.y = ((m >> (2 * grp + 1)) & 1u) ? 0.f : vy;
  *(f32x2*)(out + i0) = r;
}

extern "C" void kernel_launch(void* const* d_in, const int* in_sizes, int n_in,
                              void* d_out, int out_size, void* d_ws, size_t ws_size,
                              hipStream_t stream) {
  const float* feats = (const float*)d_in[0];
  const float* W     = (const float*)d_in[1];
  const float* b     = (const float*)d_in[2];
  const int*   ei    = (const int*)d_in[3];
  float* out = (float*)d_out;

  // ws: xb[50016*HC] bf16 | Wt[HC*KIN] bf16 | slots[NN+1] i32 | mask[NE+512] u8
  //   | bcur[NBK] i32 | csr16[NN*64] u16 | region[NBK*BCAP] u32   (~25 MB)
  char* ws = (char*)d_ws;
  size_t o = 0;
  ushort*        xb     = (ushort*)(ws + o);        o += ((size_t)50016 * HC * 2 + 255) & ~(size_t)255;
  ushort*        Wt     = (ushort*)(ws + o);        o += ((size_t)HC * KIN * 2 + 255) & ~(size_t)255;
  int*           slots  = (int*)(ws + o);           o += ((size_t)(NN + 1) * 4 + 255) & ~(size_t)255;
  unsigned char* mask   = (unsigned char*)(ws + o); o += ((size_t)NE + 512 + 255) & ~(size_t)255;
  int*           bcur   = (int*)(ws + o);           o += ((size_t)NBK * 4 + 255) & ~(size_t)255;
  ushort*        csr16  = (ushort*)(ws + o);        o += ((size_t)NN * MAXDEG * 2 + 255) & ~(size_t)255;
  unsigned*      region = (unsigned*)(ws + o);

  k_prep<<<256, 256, 0, stream>>>(W, Wt, slots, bcur);
  k_bg  <<<1763, 256, 0, stream>>>(feats, Wt, xb, ei, bcur, region, mask);
  k_csr <<<NBK, 256, 0, stream>>>(region, bcur, csr16, slots);
  k_agg <<<(NN + 3) / 4, 256, 0, stream>>>(xb, slots, csr16, mask, b, out);
}